// Round 4
// baseline (387.425 us; speedup 1.0000x reference)
//
#include <hip/hip_runtime.h>

typedef __bf16 bf16x8 __attribute__((ext_vector_type(8)));
typedef __bf16 bf16x4 __attribute__((ext_vector_type(4)));
typedef float  f32x4  __attribute__((ext_vector_type(4)));
typedef float  f32x2  __attribute__((ext_vector_type(2)));
typedef float  f32x16 __attribute__((ext_vector_type(16)));

#define BATCH 4
#define SEQ 2048
#define DMODEL 1024
#define M_ROWS (BATCH * SEQ)      // 8192
#define NCHUNK 32
#define CLEN 64
#define WXT_STRIDE 34             // pad: 34d mod 32 = 2d -> 2-way LDS alias (free)

// ---------------------------------------------------------------
// async 16B global -> LDS, gfx950
// ---------------------------------------------------------------
__device__ __forceinline__ void gload_lds16(const __bf16* g, __bf16* l) {
    __builtin_amdgcn_global_load_lds(
        (const __attribute__((address_space(1))) void*)g,
        (__attribute__((address_space(3))) void*)l, 16, 0, 0);
}

// ---------------------------------------------------------------
// Conversions + Wx transpose, one dispatch.
// ---------------------------------------------------------------
#define GX (M_ROWS * DMODEL / 4)          // 2097152
#define GW (2 * DMODEL * DMODEL / 4)      //  524288
#define GO (DMODEL * DMODEL / 4)          //  262144
#define GT (33 * DMODEL)                  //   33792
#define NTOT (GX + GW + GO + GT)

__global__ __launch_bounds__(256) void cvt_all(
    const float* __restrict__ x, const float* __restrict__ wi,
    const float* __restrict__ wo, const float* __restrict__ wx,
    __bf16* __restrict__ x_hi,
    __bf16* __restrict__ wi_hi, __bf16* __restrict__ wi_lo,
    __bf16* __restrict__ wo_b, float* __restrict__ wxT)
{
    const int g = blockIdx.x * 256 + threadIdx.x;
    if (g < GX) {
        const f32x4 v = *(const f32x4*)(x + (size_t)g * 4);
        bf16x4 h;
#pragma unroll
        for (int j = 0; j < 4; ++j) h[j] = (__bf16)v[j];
        *(bf16x4*)(x_hi + (size_t)g * 4) = h;
    } else if (g < GX + GW) {
        const int i = g - GX;
        const f32x4 v = *(const f32x4*)(wi + (size_t)i * 4);
        bf16x4 h, l;
#pragma unroll
        for (int j = 0; j < 4; ++j) {
            h[j] = (__bf16)v[j];
            l[j] = (__bf16)(v[j] - (float)h[j]);
        }
        *(bf16x4*)(wi_hi + (size_t)i * 4) = h;
        *(bf16x4*)(wi_lo + (size_t)i * 4) = l;
    } else if (g < GX + GW + GO) {
        const int i = g - GX - GW;
        const f32x4 v = *(const f32x4*)(wo + (size_t)i * 4);
        bf16x4 o;
#pragma unroll
        for (int j = 0; j < 4; ++j) o[j] = (__bf16)v[j];
        *(bf16x4*)(wo_b + (size_t)i * 4) = o;
    } else {
        const int i = g - GX - GW - GO;    // 0 .. 33*1024-1
        const int d = i / 33;
        const int e = i - d * 33;
        wxT[d * WXT_STRIDE + e] = wx[e * DMODEL + d];
    }
}

// ---------------------------------------------------------------
// Pipelined GEMM, 128 x NTILE tile, BK=32, 8 waves (2M x 4N),
// wave-tile 64x64 (2x2 MFMA 32x32x16), optional BSPLIT.
// 2-deep LDS pipeline: BSPLIT/256 -> 40KB x2 = 80KB -> 2 blocks/CU
// (cross-block overlap hides barrier drains; grid 512 = 2/CU).
// 2 kh-phases per K-tile: {frag reads, stage-next subset, barrier,
// MFMA burst (setprio), barrier}; boundary vmcnt(0) before swap.
// LDS fragment-linear: sub-tile = 32 rows x 16 k = 1KB at s*512 +
// lane*8; lane l holds row l&31, k (l>>5)*8 (verified R3 mapping).
// D layout: col=lane&31, row=(reg&3)+8*(reg>>2)+4*(lane>>5).
// ---------------------------------------------------------------
template <bool BSPLIT, int NTILE>
__global__ __launch_bounds__(512, 4) void gemm_pipe(
    const __bf16* __restrict__ A, const __bf16* __restrict__ Bh,
    const __bf16* __restrict__ Bl,
    float* __restrict__ C, int K, int N)
{
    constexpr int NBR    = NTILE / 32;              // B row-groups (8 or 4)
    constexpr int LOGNBR = (NTILE == 256) ? 3 : 2;
    constexpr int NB     = NTILE / 16;              // B sub-tiles per matrix
    constexpr int NSTT   = 8 + (BSPLIT ? 2 : 1) * NB;   // 40 or 16
    constexpr int NST    = NSTT / 8;                // per-wave stage ops (5 or 2)
    constexpr int SPL    = (NST + 1) / 2;           // stage split point
    constexpr int CN     = NTILE / 128;             // col MFMAs per wave (2 or 1)
    constexpr int BBASE  = 4096;                    // Bh elem offset
    constexpr int BUFE   = 4096 + (BSPLIT ? 2 : 1) * NTILE * 32;
    __shared__ alignas(16) __bf16 smem[2 * BUFE];

    const int lane = threadIdx.x & 63;
    const int wid  = threadIdx.x >> 6;
    const int wr   = wid >> 2;            // 0..1 : 64-row half
    const int wc   = wid & 3;             // 0..3 : 64-col quarter
    const int bm = blockIdx.y * 128;
    const int bn = blockIdx.x * NTILE;
    const int sub_r = lane & 31;          // row within 32-row sub-tile
    const int kq = (lane >> 5) * 8;       // k-offset within 16-k half
    const int NT = K / 32;

    // staging assignment: u = NST*wid + j
    //  u<8: A sub-tile u (rows (u&3)*32, khalf u>>2)
    //  else v=u-8: Bh if v<NB else Bl; s = v%NB (rows (s&(NBR-1))*32, khalf s>>LOGNBR)
    const __bf16* gS[NST];
    int sS[NST];
#pragma unroll
    for (int j = 0; j < NST; ++j) {
        const int u = NST * wid + j;
        if (u < 8) {
            const int s = u;
            gS[j] = A + (size_t)(bm + (s & 3) * 32 + sub_r) * K + (s >> 2) * 16 + kq;
            sS[j] = s * 512 + lane * 8;
        } else {
            const int v = u - 8;
            const bool lo = BSPLIT && (v >= NB);
            const int s = lo ? (v - NB) : v;
            const __bf16* src = lo ? Bl : Bh;
            gS[j] = src + (size_t)(bn + (s & (NBR - 1)) * 32 + sub_r) * K
                        + (s >> LOGNBR) * 16 + kq;
            sS[j] = BBASE + (lo ? NTILE * 32 : 0) + s * 512 + lane * 8;
        }
    }

    // prologue: stage K-tile 0
#pragma unroll
    for (int j = 0; j < NST; ++j)
        gload_lds16(gS[j], smem + sS[j]);

    f32x16 acc[2][CN] = {};

    asm volatile("s_waitcnt vmcnt(0)" ::: "memory");
    __builtin_amdgcn_s_barrier();

    for (int t = 0; t < NT; ++t) {
        const __bf16* cur = smem + (t & 1) * BUFE;
        __bf16* stg = smem + ((t + 1) & 1) * BUFE;
        const int kk = (t + 1) * 32;
        const bool more = (t + 1) < NT;

#pragma unroll
        for (int kh = 0; kh < 2; ++kh) {
            bf16x8 av[2], bh[CN], bl[CN];
#pragma unroll
            for (int rb = 0; rb < 2; ++rb)
                av[rb] = *(const bf16x8*)(cur + ((wr * 2 + rb) + kh * 4) * 512 + lane * 8);
#pragma unroll
            for (int ci = 0; ci < CN; ++ci) {
                bh[ci] = *(const bf16x8*)(cur + BBASE + ((wc * CN + ci) + kh * NBR) * 512 + lane * 8);
                if (BSPLIT)
                    bl[ci] = *(const bf16x8*)(cur + BBASE + NTILE * 32 + ((wc * CN + ci) + kh * NBR) * 512 + lane * 8);
            }
            // stage next tile: first SPL ops in kh0, rest in kh1
            if (more) {
                if (kh == 0) {
#pragma unroll
                    for (int j = 0; j < SPL; ++j)
                        gload_lds16(gS[j] + kk, stg + sS[j]);
                } else {
#pragma unroll
                    for (int j = SPL; j < NST; ++j)
                        gload_lds16(gS[j] + kk, stg + sS[j]);
                }
            }
            __builtin_amdgcn_s_barrier();
            __builtin_amdgcn_s_setprio(1);
#pragma unroll
            for (int rb = 0; rb < 2; ++rb)
#pragma unroll
                for (int ci = 0; ci < CN; ++ci) {
                    if (BSPLIT)
                        acc[rb][ci] = __builtin_amdgcn_mfma_f32_32x32x16_bf16(av[rb], bl[ci], acc[rb][ci], 0, 0, 0);
                    acc[rb][ci] = __builtin_amdgcn_mfma_f32_32x32x16_bf16(av[rb], bh[ci], acc[rb][ci], 0, 0, 0);
                }
            __builtin_amdgcn_s_setprio(0);
            if (kh == 1 && more)
                asm volatile("s_waitcnt vmcnt(0)" ::: "memory");
            if (kh == 0 || more)
                __builtin_amdgcn_s_barrier();
        }
    }

    // epilogue: D layout col=lane&31, row=(reg&3)+8*(reg>>2)+4*(lane>>5)
    const int ccol = lane & 31;
    const int rofs = 4 * (lane >> 5);
#pragma unroll
    for (int rb = 0; rb < 2; ++rb) {
#pragma unroll
        for (int ci = 0; ci < CN; ++ci) {
            const int gcol = bn + wc * (CN * 32) + ci * 32 + ccol;
#pragma unroll
            for (int reg = 0; reg < 16; ++reg) {
                const int grow = bm + wr * 64 + rb * 32 + (reg & 3) + 8 * (reg >> 2) + rofs;
                C[(size_t)grow * N + gcol] = acc[rb][ci][reg];
            }
        }
    }
}

// ---------------------------------------------------------------
// Fused conv(4)+bias+SiLU -> x_proj(+softplus).
// WxT (1024, 34-padded) f32 staged in LDS (136 KB, 1 block/CU).
// ---------------------------------------------------------------
__global__ __launch_bounds__(1024) void conv_xproj_kernel(
    const float* __restrict__ xz,
    const float* __restrict__ conv_w,
    const float* __restrict__ conv_b,
    const float* __restrict__ WxT,    // (1024, 34) f32
    float* __restrict__ x_conv,
    float* __restrict__ P)            // (M,33)
{
    __shared__ float wlds[DMODEL * WXT_STRIDE];   // 34816 f32 = 136 KB

    const int tid = threadIdx.x;
    {   // stage WxT -> LDS (coalesced f32x4 copy, once per block)
        const f32x4* src = (const f32x4*)WxT;
        f32x4* dst = (f32x4*)wlds;
        for (int i = tid; i < DMODEL * WXT_STRIDE / 4; i += 1024)
            dst[i] = src[i];
    }
    __syncthreads();

    const int wave = tid >> 6;
    const int lane = tid & 63;
    const int m = blockIdx.x * 16 + wave;
    const int l = m & (SEQ - 1);

    float acc[33];
#pragma unroll
    for (int e = 0; e < 33; ++e) acc[e] = 0.f;

    for (int d = lane; d < DMODEL; d += 64) {
        float cacc = conv_b[d];
#pragma unroll
        for (int k = 0; k < 4; ++k) {
            const int ll = l + k - 3;
            if (ll >= 0)
                cacc += xz[(size_t)(m + k - 3) * 2048 + d] * conv_w[d * 4 + k];
        }
        const float xc = cacc / (1.f + __expf(-cacc));   // SiLU
        x_conv[(size_t)m * DMODEL + d] = xc;
        const f32x2* wr = (const f32x2*)(wlds + d * WXT_STRIDE);
#pragma unroll
        for (int q = 0; q < 16; ++q) {
            const f32x2 w = wr[q];
            acc[q * 2]     += xc * w[0];
            acc[q * 2 + 1] += xc * w[1];
        }
        acc[32] += xc * wr[16][0];
    }
#pragma unroll
    for (int e = 0; e < 33; ++e) {
        float v = acc[e];
#pragma unroll
        for (int off = 32; off; off >>= 1) v += __shfl_xor(v, off, 64);
        acc[e] = v;
    }
    if (lane == 0) {
        float* out = P + (size_t)m * 33;
        for (int e = 0; e < 32; ++e) out[e] = acc[e];
        const float x = acc[32];
        out[32] = (x > 20.f) ? x : log1pf(expf(x));      // softplus
    }
}

// ---------------------------------------------------------------
// Chunked parallel scan (3 phases).
// ---------------------------------------------------------------
__global__ __launch_bounds__(256) void scan_phase1(
    const float* __restrict__ P,
    const float* __restrict__ xc,
    const float* __restrict__ A_log,
    __bf16* __restrict__ hbuf,
    float* __restrict__ S)
{
    const int d = blockIdx.x * 256 + threadIdx.x;
    const int c = blockIdx.y;
    const int b = blockIdx.z;
    const int l0 = c * CLEN;

    __shared__ float buf[CLEN * 33];
    const float* src = P + (size_t)(b * SEQ + l0) * 33;
    for (int idx = threadIdx.x; idx < CLEN * 33; idx += 256)
        buf[idx] = src[idx];
    __syncthreads();

    if (threadIdx.x == 0 && blockIdx.x == 0) {
        float s = 0.f;
        for (int j = 0; j < CLEN; ++j) s += buf[j * 33 + 32];
        S[b * NCHUNK + c] = s;
    }

    float a[16];
#pragma unroll
    for (int n = 0; n < 16; ++n) a[n] = -__expf(A_log[d * 16 + n]);
    float h[16];
#pragma unroll
    for (int n = 0; n < 16; ++n) h[n] = 0.f;

    for (int j = 0; j < CLEN; ++j) {
        const int m = b * SEQ + l0 + j;
        const float xv = xc[(size_t)m * 1024 + d];
        const float* pp = &buf[j * 33];
        const float delta = pp[32];
        const float dx = delta * xv;
#pragma unroll
        for (int n = 0; n < 16; ++n)
            h[n] = __expf(delta * a[n]) * h[n] + dx * pp[n];
    }

    __bf16* hp = hbuf + ((size_t)(b * NCHUNK + c) * 1024 + d) * 16;
#pragma unroll
    for (int n = 0; n < 16; ++n) hp[n] = (__bf16)h[n];
}

__global__ __launch_bounds__(256) void scan_phase2(
    const float* __restrict__ A_log,
    const float* __restrict__ S,
    __bf16* __restrict__ hbuf)
{
    const int n = threadIdx.x & 15;
    const int d = blockIdx.x * 16 + (threadIdx.x >> 4);
    const int b = blockIdx.y;
    const float a = -__expf(A_log[d * 16 + n]);
    float h = 0.f;
    for (int c = 0; c < NCHUNK; ++c) {
        const size_t off = ((size_t)(b * NCHUNK + c) * 1024 + d) * 16 + n;
        const float he = (float)hbuf[off];
        hbuf[off] = (__bf16)h;
        h = __expf(a * S[b * NCHUNK + c]) * h + he;
    }
}

__global__ __launch_bounds__(256) void scan_phase3(
    const float* __restrict__ P,
    const float* __restrict__ xc,
    const float* __restrict__ xz,
    const float* __restrict__ A_log,
    const float* __restrict__ Dp,
    const __bf16* __restrict__ hbuf,
    __bf16* __restrict__ Y)
{
    const int d = blockIdx.x * 256 + threadIdx.x;
    const int c = blockIdx.y;
    const int b = blockIdx.z;
    const int l0 = c * CLEN;

    __shared__ float buf[CLEN * 33];
    const float* src = P + (size_t)(b * SEQ + l0) * 33;
    for (int idx = threadIdx.x; idx < CLEN * 33; idx += 256)
        buf[idx] = src[idx];
    __syncthreads();

    float a[16];
#pragma unroll
    for (int n = 0; n < 16; ++n) a[n] = -__expf(A_log[d * 16 + n]);
    const float Dv = Dp[d];

    const __bf16* hp = hbuf + ((size_t)(b * NCHUNK + c) * 1024 + d) * 16;
    float h[16];
#pragma unroll
    for (int n = 0; n < 16; ++n) h[n] = (float)hp[n];

    for (int j = 0; j < CLEN; ++j) {
        const int m = b * SEQ + l0 + j;
        const float xv = xc[(size_t)m * 1024 + d];
        const float zv = xz[(size_t)m * 2048 + 1024 + d];
        const float* pp = &buf[j * 33];
        const float delta = pp[32];
        const float dx = delta * xv;
        float y = 0.f;
#pragma unroll
        for (int n = 0; n < 16; ++n) {
            h[n] = __expf(delta * a[n]) * h[n] + dx * pp[n];
            y += h[n] * pp[16 + n];
        }
        y += Dv * xv;
        const float sz = zv / (1.f + __expf(-zv));
        Y[(size_t)m * 1024 + d] = (__bf16)(y * sz);
    }
}

// ---------------------------------------------------------------
extern "C" void kernel_launch(void* const* d_in, const int* in_sizes, int n_in,
                              void* d_out, int out_size, void* d_ws, size_t ws_size,
                              hipStream_t stream) {
    const float* x          = (const float*)d_in[0];
    const float* in_proj_w  = (const float*)d_in[1];
    const float* conv_w     = (const float*)d_in[2];
    const float* conv_b     = (const float*)d_in[3];
    const float* x_proj_w   = (const float*)d_in[4];
    const float* A_log      = (const float*)d_in[5];
    const float* D_param    = (const float*)d_in[6];
    const float* out_proj_w = (const float*)d_in[7];
    float* out = (float*)d_out;

    char* ws = (char*)d_ws;
    float*  xz     = (float*)(ws);                 // [0, 64M)
    __bf16* x_hi   = (__bf16*)(ws + 67108864);     // [64M, 80M)
    __bf16* wi_hi  = (__bf16*)(ws + 100663296);    // [96M, 100M)
    __bf16* wi_lo  = (__bf16*)(ws + 104857600);    // [100M, 104M)
    float*  xconv  = (float*)(ws + 67108864);      // t2+: over x_hi
    float*  params = (float*)(ws + 100663296);     // t2+: over wi_hi head
    __bf16* hbuf   = (__bf16*)(ws + 101744640);    // t3: 4 MiB
    float*  Sbuf   = (float*)(ws + 105938944);     // t3: 512 B
    __bf16* y      = (__bf16*)(ws + 109051904);    // t3+: 16 MiB
    float*  wxT    = (float*)(ws + 109051904);     // t0-t2: head of y region (136KB+)
    __bf16* wo     = (__bf16*)(ws + 125829120);    // 2 MiB

    // 0) conversions + Wx transpose
    cvt_all<<<(NTOT + 255) / 256, 256, 0, stream>>>(
        x, in_proj_w, out_proj_w, x_proj_w,
        x_hi, wi_hi, wi_lo, wo, wxT);

    // 1) in_proj (M=8192,N=2048,K=1024): 128x256 tile, 2 blocks/CU
    gemm_pipe<true, 256><<<dim3(2048 / 256, M_ROWS / 128), 512, 0, stream>>>(
        x_hi, wi_hi, wi_lo, xz, DMODEL, 2048);

    // 2) fused conv+SiLU+x_proj(+softplus): LDS-staged WxT
    conv_xproj_kernel<<<M_ROWS / 16, 1024, 0, stream>>>(
        xz, conv_w, conv_b, wxT, xconv, params);

    // 3) chunked parallel scan
    scan_phase1<<<dim3(DMODEL / 256, NCHUNK, BATCH), 256, 0, stream>>>(
        params, xconv, A_log, hbuf, Sbuf);
    scan_phase2<<<dim3(DMODEL / 16, BATCH), 256, 0, stream>>>(
        A_log, Sbuf, hbuf);
    scan_phase3<<<dim3(DMODEL / 256, NCHUNK, BATCH), 256, 0, stream>>>(
        params, xconv, xz, A_log, D_param, hbuf, y);

    // 4) out_proj (M=8192,N=1024,K=1024): 128x128 tile, plain bf16
    gemm_pipe<false, 128><<<dim3(1024 / 128, M_ROWS / 128), 512, 0, stream>>>(
        y, wo, nullptr, out, DMODEL, 1024);
}

// Round 5
// 353.473 us; speedup vs baseline: 1.0961x; 1.0961x over previous
//
#include <hip/hip_runtime.h>

typedef __bf16 bf16x8 __attribute__((ext_vector_type(8)));
typedef __bf16 bf16x4 __attribute__((ext_vector_type(4)));
typedef float  f32x4  __attribute__((ext_vector_type(4)));
typedef float  f32x2  __attribute__((ext_vector_type(2)));
typedef float  f32x16 __attribute__((ext_vector_type(16)));

#define BATCH 4
#define SEQ 2048
#define DMODEL 1024
#define M_ROWS (BATCH * SEQ)      // 8192
#define NCHUNK 32
#define CLEN 64
#define WXT_STRIDE 34             // pad: 34d mod 32 = 2d -> 2-way LDS alias (free)

// ---------------------------------------------------------------
// async 16B global -> LDS, gfx950
// ---------------------------------------------------------------
__device__ __forceinline__ void gload_lds16(const __bf16* g, __bf16* l) {
    __builtin_amdgcn_global_load_lds(
        (const __attribute__((address_space(1))) void*)g,
        (__attribute__((address_space(3))) void*)l, 16, 0, 0);
}

// ---------------------------------------------------------------
// Conversions + Wx transpose, one dispatch.
// ---------------------------------------------------------------
#define GX (M_ROWS * DMODEL / 4)          // 2097152
#define GW (2 * DMODEL * DMODEL / 4)      //  524288
#define GO (DMODEL * DMODEL / 4)          //  262144
#define GT (33 * DMODEL)                  //   33792
#define NTOT (GX + GW + GO + GT)

__global__ __launch_bounds__(256) void cvt_all(
    const float* __restrict__ x, const float* __restrict__ wi,
    const float* __restrict__ wo, const float* __restrict__ wx,
    __bf16* __restrict__ x_hi,
    __bf16* __restrict__ wi_hi, __bf16* __restrict__ wi_lo,
    __bf16* __restrict__ wo_b, float* __restrict__ wxT)
{
    const int g = blockIdx.x * 256 + threadIdx.x;
    if (g < GX) {
        const f32x4 v = *(const f32x4*)(x + (size_t)g * 4);
        bf16x4 h;
#pragma unroll
        for (int j = 0; j < 4; ++j) h[j] = (__bf16)v[j];
        *(bf16x4*)(x_hi + (size_t)g * 4) = h;
    } else if (g < GX + GW) {
        const int i = g - GX;
        const f32x4 v = *(const f32x4*)(wi + (size_t)i * 4);
        bf16x4 h, l;
#pragma unroll
        for (int j = 0; j < 4; ++j) {
            h[j] = (__bf16)v[j];
            l[j] = (__bf16)(v[j] - (float)h[j]);
        }
        *(bf16x4*)(wi_hi + (size_t)i * 4) = h;
        *(bf16x4*)(wi_lo + (size_t)i * 4) = l;
    } else if (g < GX + GW + GO) {
        const int i = g - GX - GW;
        const f32x4 v = *(const f32x4*)(wo + (size_t)i * 4);
        bf16x4 o;
#pragma unroll
        for (int j = 0; j < 4; ++j) o[j] = (__bf16)v[j];
        *(bf16x4*)(wo_b + (size_t)i * 4) = o;
    } else {
        const int i = g - GX - GW - GO;    // 0 .. 33*1024-1
        const int d = i / 33;
        const int e = i - d * 33;
        wxT[d * WXT_STRIDE + e] = wx[e * DMODEL + d];
    }
}

// ---------------------------------------------------------------
// in_proj GEMM, 256x256 tile, BK=32, 8 waves (2M x 4N), BSPLIT.
// R2 geometry (verified, 72.5us) with minimal-sync loop:
//  - 3-deep LDS pipeline (3 x 48KB), stage buffer (t+2)%3 disjoint
//    from compute buffer t%3 -> ONE s_barrier + ONE counted
//    vmcnt(6) per K-tile (was 8 barriers: lockstep serialized
//    ds_read against MFMA, pinning MfmaUtil at 38%).
//  - each unique fragment read ONCE: av[8]+bh[4]+bl[4] = 16 x
//    ds_read_b128 per tile (was 32), then one 64-MFMA burst.
// LDS fragment-linear: sub-tile = 16 rows x 32 k = 1KB, lane l at
// s*512 + l*8, holds row l&15, k (l>>4)*8. 16x16x32 MFMA.
// D layout: row=(l>>4)*4+r, col=l&15 (verified R0-R2).
// ---------------------------------------------------------------
__global__ __launch_bounds__(512, 2) void gemm256_bsplit(
    const __bf16* __restrict__ A, const __bf16* __restrict__ Bh,
    const __bf16* __restrict__ Bl, float* __restrict__ C)
{
    constexpr int K = 1024, N = 2048;
    constexpr int BUFE = 3 * 8192;        // 24576 elems = 48KB per K-tile
    constexpr int NT = K / 32;            // 32 K-tiles
    __shared__ alignas(16) __bf16 smem[3 * BUFE];   // 144 KB

    const int lane = threadIdx.x & 63;
    const int wid  = threadIdx.x >> 6;
    const int wr   = wid >> 2;            // 0..1 : row-half (128 rows)
    const int wc   = wid & 3;             // 0..3 : col-quarter (64 cols)
    const int bm = blockIdx.y * 256;
    const int bn = blockIdx.x * 256;
    const int sub_r = lane & 15;
    const int kq = (lane >> 4) * 8;

    // staging: 48 sub-tiles per K-tile (A:16, Bh:16, Bl:16), 6 per wave
    const __bf16* gS[6];
    int sS[6];
#pragma unroll
    for (int j = 0; j < 6; ++j) {
        const int u = 6 * wid + j;        // 0..47
        const int mat = u >> 4;           // 0=A,1=Bh,2=Bl
        const int s = u & 15;
        const __bf16* src = (mat == 0) ? A : (mat == 1) ? Bh : Bl;
        const int rbase = (mat == 0) ? bm : bn;
        gS[j] = src + (size_t)(rbase + s * 16 + sub_r) * K + kq;
        sS[j] = mat * 8192 + s * 512 + lane * 8;
    }

    // prologue: stage K-tiles 0 and 1 (12 wave-loads)
#pragma unroll
    for (int t = 0; t < 2; ++t)
#pragma unroll
        for (int j = 0; j < 6; ++j)
            gload_lds16(gS[j] + t * 32, smem + t * BUFE + sS[j]);

    f32x4 acc[8][4] = {};

    asm volatile("s_waitcnt vmcnt(6)" ::: "memory");   // tile 0 landed
    __builtin_amdgcn_s_barrier();

    int cb3 = 0;                                       // compute buffer = t%3
    for (int t = 0; t < NT; ++t) {
        const int sb = (cb3 >= 1) ? cb3 - 1 : 2;       // stage buffer = (t+2)%3
        const __bf16* sA  = smem + cb3 * BUFE;
        const __bf16* sBh = sA + 8192;
        const __bf16* sBl = sA + 16384;
        __bf16* stg = smem + sb * BUFE;
        const int kk = (t + 2) * 32;
        const bool more = (t + 2) < NT;

        // issue next-next tile staging first (in flight during compute)
        if (more) {
#pragma unroll
            for (int j = 0; j < 6; ++j)
                gload_lds16(gS[j] + kk, stg + sS[j]);
        }

        // unique fragment reads (16 x ds_read_b128), JIT-scheduled
        bf16x8 av[8], bh[4], bl[4];
#pragma unroll
        for (int mi = 0; mi < 8; ++mi)
            av[mi] = *(const bf16x8*)(sA + (wr * 8 + mi) * 512 + lane * 8);
#pragma unroll
        for (int ni = 0; ni < 4; ++ni) {
            bh[ni] = *(const bf16x8*)(sBh + (wc * 4 + ni) * 512 + lane * 8);
            bl[ni] = *(const bf16x8*)(sBl + (wc * 4 + ni) * 512 + lane * 8);
        }

        __builtin_amdgcn_s_setprio(1);
#pragma unroll
        for (int mi = 0; mi < 8; ++mi)
#pragma unroll
            for (int ni = 0; ni < 4; ++ni) {
                acc[mi][ni] = __builtin_amdgcn_mfma_f32_16x16x32_bf16(av[mi], bl[ni], acc[mi][ni], 0, 0, 0);
                acc[mi][ni] = __builtin_amdgcn_mfma_f32_16x16x32_bf16(av[mi], bh[ni], acc[mi][ni], 0, 0, 0);
            }
        __builtin_amdgcn_s_setprio(0);

        // tile boundary: t+1's loads must be resident; t+2's stay in flight
        if (more)            { asm volatile("s_waitcnt vmcnt(6)" ::: "memory"); }
        else if (t + 1 < NT) { asm volatile("s_waitcnt vmcnt(0)" ::: "memory"); }
        if (t + 1 < NT) __builtin_amdgcn_s_barrier();

        cb3 = (cb3 >= 2) ? 0 : cb3 + 1;
    }

    // epilogue: D layout row=(l>>4)*4+r, col=l&15
    const int r_off = (lane >> 4) * 4;
    const int cc = lane & 15;
#pragma unroll
    for (int mi = 0; mi < 8; ++mi) {
        const int row0 = bm + wr * 128 + mi * 16 + r_off;
#pragma unroll
        for (int ni = 0; ni < 4; ++ni) {
            const int col = bn + wc * 64 + ni * 16 + cc;
#pragma unroll
            for (int r = 0; r < 4; ++r)
                C[(size_t)(row0 + r) * N + col] = acc[mi][ni][r];
        }
    }
}

// ---------------------------------------------------------------
// Pipelined GEMM 128x128 (2-deep), kept for out_proj (verified R4).
// ---------------------------------------------------------------
template <bool BSPLIT, int NTILE>
__global__ __launch_bounds__(512, 4) void gemm_pipe(
    const __bf16* __restrict__ A, const __bf16* __restrict__ Bh,
    const __bf16* __restrict__ Bl,
    float* __restrict__ C, int K, int N)
{
    constexpr int NBR    = NTILE / 32;
    constexpr int LOGNBR = (NTILE == 256) ? 3 : 2;
    constexpr int NB     = NTILE / 16;
    constexpr int NSTT   = 8 + (BSPLIT ? 2 : 1) * NB;
    constexpr int NST    = NSTT / 8;
    constexpr int SPL    = (NST + 1) / 2;
    constexpr int CN     = NTILE / 128;
    constexpr int BBASE  = 4096;
    constexpr int BUFE   = 4096 + (BSPLIT ? 2 : 1) * NTILE * 32;
    __shared__ alignas(16) __bf16 smem[2 * BUFE];

    const int lane = threadIdx.x & 63;
    const int wid  = threadIdx.x >> 6;
    const int wr   = wid >> 2;
    const int wc   = wid & 3;
    const int bm = blockIdx.y * 128;
    const int bn = blockIdx.x * NTILE;
    const int sub_r = lane & 31;
    const int kq = (lane >> 5) * 8;
    const int NT = K / 32;

    const __bf16* gS[NST];
    int sS[NST];
#pragma unroll
    for (int j = 0; j < NST; ++j) {
        const int u = NST * wid + j;
        if (u < 8) {
            const int s = u;
            gS[j] = A + (size_t)(bm + (s & 3) * 32 + sub_r) * K + (s >> 2) * 16 + kq;
            sS[j] = s * 512 + lane * 8;
        } else {
            const int v = u - 8;
            const bool lo = BSPLIT && (v >= NB);
            const int s = lo ? (v - NB) : v;
            const __bf16* src = lo ? Bl : Bh;
            gS[j] = src + (size_t)(bn + (s & (NBR - 1)) * 32 + sub_r) * K
                        + (s >> LOGNBR) * 16 + kq;
            sS[j] = BBASE + (lo ? NTILE * 32 : 0) + s * 512 + lane * 8;
        }
    }

#pragma unroll
    for (int j = 0; j < NST; ++j)
        gload_lds16(gS[j], smem + sS[j]);

    f32x16 acc[2][CN] = {};

    asm volatile("s_waitcnt vmcnt(0)" ::: "memory");
    __builtin_amdgcn_s_barrier();

    for (int t = 0; t < NT; ++t) {
        const __bf16* cur = smem + (t & 1) * BUFE;
        __bf16* stg = smem + ((t + 1) & 1) * BUFE;
        const int kk = (t + 1) * 32;
        const bool more = (t + 1) < NT;

#pragma unroll
        for (int kh = 0; kh < 2; ++kh) {
            bf16x8 av[2], bh[CN], bl[CN];
#pragma unroll
            for (int rb = 0; rb < 2; ++rb)
                av[rb] = *(const bf16x8*)(cur + ((wr * 2 + rb) + kh * 4) * 512 + lane * 8);
#pragma unroll
            for (int ci = 0; ci < CN; ++ci) {
                bh[ci] = *(const bf16x8*)(cur + BBASE + ((wc * CN + ci) + kh * NBR) * 512 + lane * 8);
                if (BSPLIT)
                    bl[ci] = *(const bf16x8*)(cur + BBASE + NTILE * 32 + ((wc * CN + ci) + kh * NBR) * 512 + lane * 8);
            }
            if (more) {
                if (kh == 0) {
#pragma unroll
                    for (int j = 0; j < SPL; ++j)
                        gload_lds16(gS[j] + kk, stg + sS[j]);
                } else {
#pragma unroll
                    for (int j = SPL; j < NST; ++j)
                        gload_lds16(gS[j] + kk, stg + sS[j]);
                }
            }
            __builtin_amdgcn_s_barrier();
            __builtin_amdgcn_s_setprio(1);
#pragma unroll
            for (int rb = 0; rb < 2; ++rb)
#pragma unroll
                for (int ci = 0; ci < CN; ++ci) {
                    if (BSPLIT)
                        acc[rb][ci] = __builtin_amdgcn_mfma_f32_32x32x16_bf16(av[rb], bl[ci], acc[rb][ci], 0, 0, 0);
                    acc[rb][ci] = __builtin_amdgcn_mfma_f32_32x32x16_bf16(av[rb], bh[ci], acc[rb][ci], 0, 0, 0);
                }
            __builtin_amdgcn_s_setprio(0);
            if (kh == 1 && more)
                asm volatile("s_waitcnt vmcnt(0)" ::: "memory");
            if (kh == 0 || more)
                __builtin_amdgcn_s_barrier();
        }
    }

    const int ccol = lane & 31;
    const int rofs = 4 * (lane >> 5);
#pragma unroll
    for (int rb = 0; rb < 2; ++rb) {
#pragma unroll
        for (int ci = 0; ci < CN; ++ci) {
            const int gcol = bn + wc * (CN * 32) + ci * 32 + ccol;
#pragma unroll
            for (int reg = 0; reg < 16; ++reg) {
                const int grow = bm + wr * 64 + rb * 32 + (reg & 3) + 8 * (reg >> 2) + rofs;
                C[(size_t)grow * N + gcol] = acc[rb][ci][reg];
            }
        }
    }
}

// ---------------------------------------------------------------
// Fused conv(4)+bias+SiLU -> x_proj(+softplus).
// WxT (1024, 34-padded) f32 staged in LDS (136 KB, 1 block/CU).
// ---------------------------------------------------------------
__global__ __launch_bounds__(1024) void conv_xproj_kernel(
    const float* __restrict__ xz,
    const float* __restrict__ conv_w,
    const float* __restrict__ conv_b,
    const float* __restrict__ WxT,    // (1024, 34) f32
    float* __restrict__ x_conv,
    float* __restrict__ P)            // (M,33)
{
    __shared__ float wlds[DMODEL * WXT_STRIDE];   // 34816 f32 = 136 KB

    const int tid = threadIdx.x;
    {
        const f32x4* src = (const f32x4*)WxT;
        f32x4* dst = (f32x4*)wlds;
        for (int i = tid; i < DMODEL * WXT_STRIDE / 4; i += 1024)
            dst[i] = src[i];
    }
    __syncthreads();

    const int wave = tid >> 6;
    const int lane = tid & 63;
    const int m = blockIdx.x * 16 + wave;
    const int l = m & (SEQ - 1);

    float acc[33];
#pragma unroll
    for (int e = 0; e < 33; ++e) acc[e] = 0.f;

    for (int d = lane; d < DMODEL; d += 64) {
        float cacc = conv_b[d];
#pragma unroll
        for (int k = 0; k < 4; ++k) {
            const int ll = l + k - 3;
            if (ll >= 0)
                cacc += xz[(size_t)(m + k - 3) * 2048 + d] * conv_w[d * 4 + k];
        }
        const float xc = cacc / (1.f + __expf(-cacc));   // SiLU
        x_conv[(size_t)m * DMODEL + d] = xc;
        const f32x2* wr = (const f32x2*)(wlds + d * WXT_STRIDE);
#pragma unroll
        for (int q = 0; q < 16; ++q) {
            const f32x2 w = wr[q];
            acc[q * 2]     += xc * w[0];
            acc[q * 2 + 1] += xc * w[1];
        }
        acc[32] += xc * wr[16][0];
    }
#pragma unroll
    for (int e = 0; e < 33; ++e) {
        float v = acc[e];
#pragma unroll
        for (int off = 32; off; off >>= 1) v += __shfl_xor(v, off, 64);
        acc[e] = v;
    }
    if (lane == 0) {
        float* out = P + (size_t)m * 33;
        for (int e = 0; e < 32; ++e) out[e] = acc[e];
        const float x = acc[32];
        out[32] = (x > 20.f) ? x : log1pf(expf(x));      // softplus
    }
}

// ---------------------------------------------------------------
// Chunked parallel scan (3 phases).
// ---------------------------------------------------------------
__global__ __launch_bounds__(256) void scan_phase1(
    const float* __restrict__ P,
    const float* __restrict__ xc,
    const float* __restrict__ A_log,
    __bf16* __restrict__ hbuf,
    float* __restrict__ S)
{
    const int d = blockIdx.x * 256 + threadIdx.x;
    const int c = blockIdx.y;
    const int b = blockIdx.z;
    const int l0 = c * CLEN;

    __shared__ float buf[CLEN * 33];
    const float* src = P + (size_t)(b * SEQ + l0) * 33;
    for (int idx = threadIdx.x; idx < CLEN * 33; idx += 256)
        buf[idx] = src[idx];
    __syncthreads();

    if (threadIdx.x == 0 && blockIdx.x == 0) {
        float s = 0.f;
        for (int j = 0; j < CLEN; ++j) s += buf[j * 33 + 32];
        S[b * NCHUNK + c] = s;
    }

    float a[16];
#pragma unroll
    for (int n = 0; n < 16; ++n) a[n] = -__expf(A_log[d * 16 + n]);
    float h[16];
#pragma unroll
    for (int n = 0; n < 16; ++n) h[n] = 0.f;

    for (int j = 0; j < CLEN; ++j) {
        const int m = b * SEQ + l0 + j;
        const float xv = xc[(size_t)m * 1024 + d];
        const float* pp = &buf[j * 33];
        const float delta = pp[32];
        const float dx = delta * xv;
#pragma unroll
        for (int n = 0; n < 16; ++n)
            h[n] = __expf(delta * a[n]) * h[n] + dx * pp[n];
    }

    __bf16* hp = hbuf + ((size_t)(b * NCHUNK + c) * 1024 + d) * 16;
#pragma unroll
    for (int n = 0; n < 16; ++n) hp[n] = (__bf16)h[n];
}

__global__ __launch_bounds__(256) void scan_phase2(
    const float* __restrict__ A_log,
    const float* __restrict__ S,
    __bf16* __restrict__ hbuf)
{
    const int n = threadIdx.x & 15;
    const int d = blockIdx.x * 16 + (threadIdx.x >> 4);
    const int b = blockIdx.y;
    const float a = -__expf(A_log[d * 16 + n]);
    float h = 0.f;
    for (int c = 0; c < NCHUNK; ++c) {
        const size_t off = ((size_t)(b * NCHUNK + c) * 1024 + d) * 16 + n;
        const float he = (float)hbuf[off];
        hbuf[off] = (__bf16)h;
        h = __expf(a * S[b * NCHUNK + c]) * h + he;
    }
}

__global__ __launch_bounds__(256) void scan_phase3(
    const float* __restrict__ P,
    const float* __restrict__ xc,
    const float* __restrict__ xz,
    const float* __restrict__ A_log,
    const float* __restrict__ Dp,
    const __bf16* __restrict__ hbuf,
    __bf16* __restrict__ Y)
{
    const int d = blockIdx.x * 256 + threadIdx.x;
    const int c = blockIdx.y;
    const int b = blockIdx.z;
    const int l0 = c * CLEN;

    __shared__ float buf[CLEN * 33];
    const float* src = P + (size_t)(b * SEQ + l0) * 33;
    for (int idx = threadIdx.x; idx < CLEN * 33; idx += 256)
        buf[idx] = src[idx];
    __syncthreads();

    float a[16];
#pragma unroll
    for (int n = 0; n < 16; ++n) a[n] = -__expf(A_log[d * 16 + n]);
    const float Dv = Dp[d];

    const __bf16* hp = hbuf + ((size_t)(b * NCHUNK + c) * 1024 + d) * 16;
    float h[16];
#pragma unroll
    for (int n = 0; n < 16; ++n) h[n] = (float)hp[n];

    for (int j = 0; j < CLEN; ++j) {
        const int m = b * SEQ + l0 + j;
        const float xv = xc[(size_t)m * 1024 + d];
        const float zv = xz[(size_t)m * 2048 + 1024 + d];
        const float* pp = &buf[j * 33];
        const float delta = pp[32];
        const float dx = delta * xv;
        float y = 0.f;
#pragma unroll
        for (int n = 0; n < 16; ++n) {
            h[n] = __expf(delta * a[n]) * h[n] + dx * pp[n];
            y += h[n] * pp[16 + n];
        }
        y += Dv * xv;
        const float sz = zv / (1.f + __expf(-zv));
        Y[(size_t)m * 1024 + d] = (__bf16)(y * sz);
    }
}

// ---------------------------------------------------------------
extern "C" void kernel_launch(void* const* d_in, const int* in_sizes, int n_in,
                              void* d_out, int out_size, void* d_ws, size_t ws_size,
                              hipStream_t stream) {
    const float* x          = (const float*)d_in[0];
    const float* in_proj_w  = (const float*)d_in[1];
    const float* conv_w     = (const float*)d_in[2];
    const float* conv_b     = (const float*)d_in[3];
    const float* x_proj_w   = (const float*)d_in[4];
    const float* A_log      = (const float*)d_in[5];
    const float* D_param    = (const float*)d_in[6];
    const float* out_proj_w = (const float*)d_in[7];
    float* out = (float*)d_out;

    char* ws = (char*)d_ws;
    float*  xz     = (float*)(ws);                 // [0, 64M)
    __bf16* x_hi   = (__bf16*)(ws + 67108864);     // [64M, 80M)
    __bf16* wi_hi  = (__bf16*)(ws + 100663296);    // [96M, 100M)
    __bf16* wi_lo  = (__bf16*)(ws + 104857600);    // [100M, 104M)
    float*  xconv  = (float*)(ws + 67108864);      // t2+: over x_hi
    float*  params = (float*)(ws + 100663296);     // t2+: over wi_hi head
    __bf16* hbuf   = (__bf16*)(ws + 101744640);    // t3: 4 MiB
    float*  Sbuf   = (float*)(ws + 105938944);     // t3: 512 B
    __bf16* y      = (__bf16*)(ws + 109051904);    // t3+: 16 MiB
    float*  wxT    = (float*)(ws + 109051904);     // t0-t2: head of y region (136KB+)
    __bf16* wo     = (__bf16*)(ws + 125829120);    // 2 MiB

    // 0) conversions + Wx transpose
    cvt_all<<<(NTOT + 255) / 256, 256, 0, stream>>>(
        x, in_proj_w, out_proj_w, x_proj_w,
        x_hi, wi_hi, wi_lo, wo, wxT);

    // 1) in_proj (M=8192,N=2048,K=1024): 256^2 tile, 1-barrier/K-tile
    gemm256_bsplit<<<dim3(2048 / 256, M_ROWS / 256), 512, 0, stream>>>(
        x_hi, wi_hi, wi_lo, xz);

    // 2) fused conv+SiLU+x_proj(+softplus): LDS-staged WxT
    conv_xproj_kernel<<<M_ROWS / 16, 1024, 0, stream>>>(
        xz, conv_w, conv_b, wxT, xconv, params);

    // 3) chunked parallel scan
    scan_phase1<<<dim3(DMODEL / 256, NCHUNK, BATCH), 256, 0, stream>>>(
        params, xconv, A_log, hbuf, Sbuf);
    scan_phase2<<<dim3(DMODEL / 16, BATCH), 256, 0, stream>>>(
        A_log, Sbuf, hbuf);
    scan_phase3<<<dim3(DMODEL / 256, NCHUNK, BATCH), 256, 0, stream>>>(
        params, xconv, xz, A_log, D_param, hbuf, y);

    // 4) out_proj (M=8192,N=1024,K=1024): 128x128 tile, plain bf16
    gemm_pipe<false, 128><<<dim3(1024 / 128, M_ROWS / 128), 512, 0, stream>>>(
        y, wo, nullptr, out, DMODEL, 1024);
}

// Round 7
// 331.610 us; speedup vs baseline: 1.1683x; 1.0659x over previous
//
#include <hip/hip_runtime.h>

typedef __bf16 bf16x8 __attribute__((ext_vector_type(8)));
typedef __bf16 bf16x4 __attribute__((ext_vector_type(4)));
typedef float  f32x4  __attribute__((ext_vector_type(4)));
typedef float  f32x2  __attribute__((ext_vector_type(2)));
typedef float  f32x16 __attribute__((ext_vector_type(16)));

#define BATCH 4
#define SEQ 2048
#define DMODEL 1024
#define M_ROWS (BATCH * SEQ)      // 8192
#define NCHUNK 32
#define CLEN 64

// ---------------------------------------------------------------
// async 16B global -> LDS, gfx950
// ---------------------------------------------------------------
__device__ __forceinline__ void gload_lds16(const __bf16* g, __bf16* l) {
    __builtin_amdgcn_global_load_lds(
        (const __attribute__((address_space(1))) void*)g,
        (__attribute__((address_space(3))) void*)l, 16, 0, 0);
}

// ---------------------------------------------------------------
// Conversions, one dispatch:
//  A: x -> bf16 (trunc)          B: in_proj_w -> hi/lo split
//  C: out_proj_w -> bf16         D: x_proj_w -> Wh/Wl bf16 (48x1024,
//     zero-padded rows 33..47)   E: conv_w -> cwT[k][d] f32
// ---------------------------------------------------------------
#define GX (M_ROWS * DMODEL / 4)          // 2097152
#define GW (2 * DMODEL * DMODEL / 4)      //  524288
#define GO (DMODEL * DMODEL / 4)          //  262144
#define GT (48 * DMODEL)                  //   49152
#define GC (4 * DMODEL)                   //    4096
#define NTOT (GX + GW + GO + GT + GC)

__global__ __launch_bounds__(256) void cvt_all(
    const float* __restrict__ x, const float* __restrict__ wi,
    const float* __restrict__ wo, const float* __restrict__ wx,
    const float* __restrict__ cw,
    __bf16* __restrict__ x_hi,
    __bf16* __restrict__ wi_hi, __bf16* __restrict__ wi_lo,
    __bf16* __restrict__ wo_b,
    __bf16* __restrict__ wxh, __bf16* __restrict__ wxl,
    float* __restrict__ cwT)
{
    const int g = blockIdx.x * 256 + threadIdx.x;
    if (g < GX) {
        const f32x4 v = *(const f32x4*)(x + (size_t)g * 4);
        bf16x4 h;
#pragma unroll
        for (int j = 0; j < 4; ++j) h[j] = (__bf16)v[j];
        *(bf16x4*)(x_hi + (size_t)g * 4) = h;
    } else if (g < GX + GW) {
        const int i = g - GX;
        const f32x4 v = *(const f32x4*)(wi + (size_t)i * 4);
        bf16x4 h, l;
#pragma unroll
        for (int j = 0; j < 4; ++j) {
            h[j] = (__bf16)v[j];
            l[j] = (__bf16)(v[j] - (float)h[j]);
        }
        *(bf16x4*)(wi_hi + (size_t)i * 4) = h;
        *(bf16x4*)(wi_lo + (size_t)i * 4) = l;
    } else if (g < GX + GW + GO) {
        const int i = g - GX - GW;
        const f32x4 v = *(const f32x4*)(wo + (size_t)i * 4);
        bf16x4 o;
#pragma unroll
        for (int j = 0; j < 4; ++j) o[j] = (__bf16)v[j];
        *(bf16x4*)(wo_b + (size_t)i * 4) = o;
    } else if (g < GX + GW + GO + GT) {
        const int i = g - GX - GW - GO;   // 0 .. 48*1024-1
        const int e = i >> 10;
        const float v = (e < 33) ? wx[i] : 0.f;
        const __bf16 h = (__bf16)v;
        wxh[i] = h;
        wxl[i] = (__bf16)(v - (float)h);
    } else {
        const int i = g - GX - GW - GO - GT;  // 0 .. 4*1024-1
        const int k = i >> 10;
        const int d = i & 1023;
        cwT[i] = cw[d * 4 + k];
    }
}

// ---------------------------------------------------------------
// in_proj GEMM, 256x256 tile, BK=32, 8 waves (2M x 4N), BSPLIT.
// R5 minimal-sync loop (verified): 3-deep LDS pipeline, ONE
// s_barrier + ONE counted vmcnt(6) per K-tile, fragments read once.
// ---------------------------------------------------------------
__global__ __launch_bounds__(512, 2) void gemm256_bsplit(
    const __bf16* __restrict__ A, const __bf16* __restrict__ Bh,
    const __bf16* __restrict__ Bl, float* __restrict__ C)
{
    constexpr int K = 1024, N = 2048;
    constexpr int BUFE = 3 * 8192;        // 24576 elems = 48KB per K-tile
    constexpr int NT = K / 32;            // 32 K-tiles
    __shared__ alignas(16) __bf16 smem[3 * BUFE];   // 144 KB

    const int lane = threadIdx.x & 63;
    const int wid  = threadIdx.x >> 6;
    const int wr   = wid >> 2;
    const int wc   = wid & 3;
    const int bm = blockIdx.y * 256;
    const int bn = blockIdx.x * 256;
    const int sub_r = lane & 15;
    const int kq = (lane >> 4) * 8;

    const __bf16* gS[6];
    int sS[6];
#pragma unroll
    for (int j = 0; j < 6; ++j) {
        const int u = 6 * wid + j;
        const int mat = u >> 4;
        const int s = u & 15;
        const __bf16* src = (mat == 0) ? A : (mat == 1) ? Bh : Bl;
        const int rbase = (mat == 0) ? bm : bn;
        gS[j] = src + (size_t)(rbase + s * 16 + sub_r) * K + kq;
        sS[j] = mat * 8192 + s * 512 + lane * 8;
    }

#pragma unroll
    for (int t = 0; t < 2; ++t)
#pragma unroll
        for (int j = 0; j < 6; ++j)
            gload_lds16(gS[j] + t * 32, smem + t * BUFE + sS[j]);

    f32x4 acc[8][4] = {};

    asm volatile("s_waitcnt vmcnt(6)" ::: "memory");
    __builtin_amdgcn_s_barrier();

    int cb3 = 0;
    for (int t = 0; t < NT; ++t) {
        const int sb = (cb3 >= 1) ? cb3 - 1 : 2;
        const __bf16* sA  = smem + cb3 * BUFE;
        const __bf16* sBh = sA + 8192;
        const __bf16* sBl = sA + 16384;
        __bf16* stg = smem + sb * BUFE;
        const int kk = (t + 2) * 32;
        const bool more = (t + 2) < NT;

        if (more) {
#pragma unroll
            for (int j = 0; j < 6; ++j)
                gload_lds16(gS[j] + kk, stg + sS[j]);
        }

        bf16x8 av[8], bh[4], bl[4];
#pragma unroll
        for (int mi = 0; mi < 8; ++mi)
            av[mi] = *(const bf16x8*)(sA + (wr * 8 + mi) * 512 + lane * 8);
#pragma unroll
        for (int ni = 0; ni < 4; ++ni) {
            bh[ni] = *(const bf16x8*)(sBh + (wc * 4 + ni) * 512 + lane * 8);
            bl[ni] = *(const bf16x8*)(sBl + (wc * 4 + ni) * 512 + lane * 8);
        }

        __builtin_amdgcn_s_setprio(1);
#pragma unroll
        for (int mi = 0; mi < 8; ++mi)
#pragma unroll
            for (int ni = 0; ni < 4; ++ni) {
                acc[mi][ni] = __builtin_amdgcn_mfma_f32_16x16x32_bf16(av[mi], bl[ni], acc[mi][ni], 0, 0, 0);
                acc[mi][ni] = __builtin_amdgcn_mfma_f32_16x16x32_bf16(av[mi], bh[ni], acc[mi][ni], 0, 0, 0);
            }
        __builtin_amdgcn_s_setprio(0);

        if (more)            { asm volatile("s_waitcnt vmcnt(6)" ::: "memory"); }
        else if (t + 1 < NT) { asm volatile("s_waitcnt vmcnt(0)" ::: "memory"); }
        if (t + 1 < NT) __builtin_amdgcn_s_barrier();

        cb3 = (cb3 >= 2) ? 0 : cb3 + 1;
    }

    const int r_off = (lane >> 4) * 4;
    const int cc = lane & 15;
#pragma unroll
    for (int mi = 0; mi < 8; ++mi) {
        const int row0 = bm + wr * 128 + mi * 16 + r_off;
#pragma unroll
        for (int ni = 0; ni < 4; ++ni) {
            const int col = bn + wc * 64 + ni * 16 + cc;
#pragma unroll
            for (int r = 0; r < 4; ++r)
                C[(size_t)(row0 + r) * N + col] = acc[mi][ni][r];
        }
    }
}

// ---------------------------------------------------------------
// Pipelined GEMM 128x128 (2-deep), kept for out_proj (verified R4).
// ---------------------------------------------------------------
template <bool BSPLIT, int NTILE>
__global__ __launch_bounds__(512, 4) void gemm_pipe(
    const __bf16* __restrict__ A, const __bf16* __restrict__ Bh,
    const __bf16* __restrict__ Bl,
    float* __restrict__ C, int K, int N)
{
    constexpr int NBR    = NTILE / 32;
    constexpr int LOGNBR = (NTILE == 256) ? 3 : 2;
    constexpr int NB     = NTILE / 16;
    constexpr int NSTT   = 8 + (BSPLIT ? 2 : 1) * NB;
    constexpr int NST    = NSTT / 8;
    constexpr int SPL    = (NST + 1) / 2;
    constexpr int CN     = NTILE / 128;
    constexpr int BBASE  = 4096;
    constexpr int BUFE   = 4096 + (BSPLIT ? 2 : 1) * NTILE * 32;
    __shared__ alignas(16) __bf16 smem[2 * BUFE];

    const int lane = threadIdx.x & 63;
    const int wid  = threadIdx.x >> 6;
    const int wr   = wid >> 2;
    const int wc   = wid & 3;
    const int bm = blockIdx.y * 128;
    const int bn = blockIdx.x * NTILE;
    const int sub_r = lane & 31;
    const int kq = (lane >> 5) * 8;
    const int NT = K / 32;

    const __bf16* gS[NST];
    int sS[NST];
#pragma unroll
    for (int j = 0; j < NST; ++j) {
        const int u = NST * wid + j;
        if (u < 8) {
            const int s = u;
            gS[j] = A + (size_t)(bm + (s & 3) * 32 + sub_r) * K + (s >> 2) * 16 + kq;
            sS[j] = s * 512 + lane * 8;
        } else {
            const int v = u - 8;
            const bool lo = BSPLIT && (v >= NB);
            const int s = lo ? (v - NB) : v;
            const __bf16* src = lo ? Bl : Bh;
            gS[j] = src + (size_t)(bn + (s & (NBR - 1)) * 32 + sub_r) * K
                        + (s >> LOGNBR) * 16 + kq;
            sS[j] = BBASE + (lo ? NTILE * 32 : 0) + s * 512 + lane * 8;
        }
    }

#pragma unroll
    for (int j = 0; j < NST; ++j)
        gload_lds16(gS[j], smem + sS[j]);

    f32x16 acc[2][CN] = {};

    asm volatile("s_waitcnt vmcnt(0)" ::: "memory");
    __builtin_amdgcn_s_barrier();

    for (int t = 0; t < NT; ++t) {
        const __bf16* cur = smem + (t & 1) * BUFE;
        __bf16* stg = smem + ((t + 1) & 1) * BUFE;
        const int kk = (t + 1) * 32;
        const bool more = (t + 1) < NT;

#pragma unroll
        for (int kh = 0; kh < 2; ++kh) {
            bf16x8 av[2], bh[CN], bl[CN];
#pragma unroll
            for (int rb = 0; rb < 2; ++rb)
                av[rb] = *(const bf16x8*)(cur + ((wr * 2 + rb) + kh * 4) * 512 + lane * 8);
#pragma unroll
            for (int ci = 0; ci < CN; ++ci) {
                bh[ci] = *(const bf16x8*)(cur + BBASE + ((wc * CN + ci) + kh * NBR) * 512 + lane * 8);
                if (BSPLIT)
                    bl[ci] = *(const bf16x8*)(cur + BBASE + NTILE * 32 + ((wc * CN + ci) + kh * NBR) * 512 + lane * 8);
            }
            if (more) {
                if (kh == 0) {
#pragma unroll
                    for (int j = 0; j < SPL; ++j)
                        gload_lds16(gS[j] + kk, stg + sS[j]);
                } else {
#pragma unroll
                    for (int j = SPL; j < NST; ++j)
                        gload_lds16(gS[j] + kk, stg + sS[j]);
                }
            }
            __builtin_amdgcn_s_barrier();
            __builtin_amdgcn_s_setprio(1);
#pragma unroll
            for (int rb = 0; rb < 2; ++rb)
#pragma unroll
                for (int ci = 0; ci < CN; ++ci) {
                    if (BSPLIT)
                        acc[rb][ci] = __builtin_amdgcn_mfma_f32_32x32x16_bf16(av[rb], bl[ci], acc[rb][ci], 0, 0, 0);
                    acc[rb][ci] = __builtin_amdgcn_mfma_f32_32x32x16_bf16(av[rb], bh[ci], acc[rb][ci], 0, 0, 0);
                }
            __builtin_amdgcn_s_setprio(0);
            if (kh == 1 && more)
                asm volatile("s_waitcnt vmcnt(0)" ::: "memory");
            if (kh == 0 || more)
                __builtin_amdgcn_s_barrier();
        }
    }

    const int ccol = lane & 31;
    const int rofs = 4 * (lane >> 5);
#pragma unroll
    for (int rb = 0; rb < 2; ++rb) {
#pragma unroll
        for (int ci = 0; ci < CN; ++ci) {
            const int gcol = bn + wc * (CN * 32) + ci * 32 + ccol;
#pragma unroll
            for (int reg = 0; reg < 16; ++reg) {
                const int grow = bm + wr * 64 + rb * 32 + (reg & 3) + 8 * (reg >> 2) + rofs;
                C[(size_t)grow * N + gcol] = acc[rb][ci][reg];
            }
        }
    }
}

// ---------------------------------------------------------------
// conv(4)+bias+SiLU, streaming: one row per block, f32x4 per thread.
// Writes x_conv as exact bf16 hi/lo split (xch + xcl).
// ---------------------------------------------------------------
__global__ __launch_bounds__(256) void conv_silu(
    const float* __restrict__ xz,
    const float* __restrict__ cwT,    // (4, 1024) f32
    const float* __restrict__ conv_b,
    __bf16* __restrict__ xch, __bf16* __restrict__ xcl)
{
    const int m = blockIdx.x;
    const int l = m & (SEQ - 1);
    const int dq = threadIdx.x * 4;

    f32x4 acc = *(const f32x4*)(conv_b + dq);
#pragma unroll
    for (int k = 0; k < 4; ++k) {
        if (l + k - 3 >= 0) {
            const f32x4 xv = *(const f32x4*)(xz + (size_t)(m + k - 3) * 2048 + dq);
            const f32x4 wv = *(const f32x4*)(cwT + k * DMODEL + dq);
#pragma unroll
            for (int j = 0; j < 4; ++j) acc[j] += xv[j] * wv[j];
        }
    }
    bf16x4 h, lo;
#pragma unroll
    for (int j = 0; j < 4; ++j) {
        const float xc = acc[j] / (1.f + __expf(-acc[j]));   // SiLU
        h[j]  = (__bf16)xc;
        lo[j] = (__bf16)(xc - (float)h[j]);
    }
    *(bf16x4*)(xch + (size_t)m * DMODEL + dq) = h;
    *(bf16x4*)(xcl + (size_t)m * DMODEL + dq) = lo;
}

// ---------------------------------------------------------------
// x_proj as MFMA GEMM: P(M,33) = xc @ W^T, 3-term split
// (xch@Wl + xch@Wh + xcl@Wh), W zero-padded to 48 rows.
// M-tile 32, 2 waves (one 16-row m-frag each), 256 blocks.
// R5 minimal-sync 3-deep pipeline, counted vmcnt(5).
// Softplus fused on col 32. D layout: row=(l>>4)*4+r, col=l&15.
// ---------------------------------------------------------------
__global__ __launch_bounds__(128) void xproj_gemm(
    const __bf16* __restrict__ Ah, const __bf16* __restrict__ Al,
    const __bf16* __restrict__ Wh, const __bf16* __restrict__ Wl,
    float* __restrict__ P)
{
    constexpr int K = 1024;
    constexpr int NT = K / 32;
    constexpr int BUFE = 5120;            // 10 subtiles x 512 elems = 10 KB
    __shared__ alignas(16) __bf16 smem[3 * BUFE];   // 30 KB

    const int lane = threadIdx.x & 63;
    const int wave = threadIdx.x >> 6;    // 0..1
    const int bm = blockIdx.x * 32;
    const int sub_r = lane & 15;
    const int kq = (lane >> 4) * 8;

    // subtiles u=0..9: 0-1 Ah, 2-3 Al, 4-6 Wh, 7-9 Wl; 5 per wave
    const __bf16* gS[5];
    int sS[5];
#pragma unroll
    for (int j = 0; j < 5; ++j) {
        const int u = 5 * wave + j;
        const __bf16* src;
        int row;
        if (u < 2)      { src = Ah; row = bm + u * 16 + sub_r; }
        else if (u < 4) { src = Al; row = bm + (u - 2) * 16 + sub_r; }
        else if (u < 7) { src = Wh; row = (u - 4) * 16 + sub_r; }
        else            { src = Wl; row = (u - 7) * 16 + sub_r; }
        gS[j] = src + (size_t)row * K + kq;
        sS[j] = u * 512 + lane * 8;
    }

#pragma unroll
    for (int t = 0; t < 2; ++t)
#pragma unroll
        for (int j = 0; j < 5; ++j)
            gload_lds16(gS[j] + t * 32, smem + t * BUFE + sS[j]);

    f32x4 acc[3] = {};

    asm volatile("s_waitcnt vmcnt(5)" ::: "memory");
    __builtin_amdgcn_s_barrier();

    int cb3 = 0;
    for (int t = 0; t < NT; ++t) {
        const int sb = (cb3 >= 1) ? cb3 - 1 : 2;
        const __bf16* cur = smem + cb3 * BUFE;
        __bf16* stg = smem + sb * BUFE;
        const int kk = (t + 2) * 32;
        const bool more = (t + 2) < NT;

        if (more) {
#pragma unroll
            for (int j = 0; j < 5; ++j)
                gload_lds16(gS[j] + kk, stg + sS[j]);
        }

        bf16x8 ah, al, wh[3], wl[3];
        ah = *(const bf16x8*)(cur + (0 + wave) * 512 + lane * 8);
        al = *(const bf16x8*)(cur + (2 + wave) * 512 + lane * 8);
#pragma unroll
        for (int n = 0; n < 3; ++n) {
            wh[n] = *(const bf16x8*)(cur + (4 + n) * 512 + lane * 8);
            wl[n] = *(const bf16x8*)(cur + (7 + n) * 512 + lane * 8);
        }

#pragma unroll
        for (int n = 0; n < 3; ++n) {
            acc[n] = __builtin_amdgcn_mfma_f32_16x16x32_bf16(ah, wl[n], acc[n], 0, 0, 0);
            acc[n] = __builtin_amdgcn_mfma_f32_16x16x32_bf16(al, wh[n], acc[n], 0, 0, 0);
            acc[n] = __builtin_amdgcn_mfma_f32_16x16x32_bf16(ah, wh[n], acc[n], 0, 0, 0);
        }

        if (more)            { asm volatile("s_waitcnt vmcnt(5)" ::: "memory"); }
        else if (t + 1 < NT) { asm volatile("s_waitcnt vmcnt(0)" ::: "memory"); }
        if (t + 1 < NT) __builtin_amdgcn_s_barrier();

        cb3 = (cb3 >= 2) ? 0 : cb3 + 1;
    }

    // epilogue: row=(l>>4)*4+r, col=n*16+(l&15); write cols < 33
    const int r_off = (lane >> 4) * 4;
    const int cc = lane & 15;
#pragma unroll
    for (int n = 0; n < 3; ++n) {
        const int col = n * 16 + cc;
        if (col < 33) {
#pragma unroll
            for (int r = 0; r < 4; ++r) {
                const int row = bm + wave * 16 + r_off + r;
                float v = acc[n][r];
                if (col == 32) v = (v > 20.f) ? v : log1pf(expf(v));  // softplus
                P[(size_t)row * 33 + col] = v;
            }
        }
    }
}

// ---------------------------------------------------------------
// Chunked parallel scan (3 phases). xc read as bf16 hi+lo.
// ---------------------------------------------------------------
__global__ __launch_bounds__(256) void scan_phase1(
    const float* __restrict__ P,
    const __bf16* __restrict__ xch, const __bf16* __restrict__ xcl,
    const float* __restrict__ A_log,
    __bf16* __restrict__ hbuf,
    float* __restrict__ S)
{
    const int d = blockIdx.x * 256 + threadIdx.x;
    const int c = blockIdx.y;
    const int b = blockIdx.z;
    const int l0 = c * CLEN;

    __shared__ float buf[CLEN * 33];
    const float* src = P + (size_t)(b * SEQ + l0) * 33;
    for (int idx = threadIdx.x; idx < CLEN * 33; idx += 256)
        buf[idx] = src[idx];
    __syncthreads();

    if (threadIdx.x == 0 && blockIdx.x == 0) {
        float s = 0.f;
        for (int j = 0; j < CLEN; ++j) s += buf[j * 33 + 32];
        S[b * NCHUNK + c] = s;
    }

    float a[16];
#pragma unroll
    for (int n = 0; n < 16; ++n) a[n] = -__expf(A_log[d * 16 + n]);
    float h[16];
#pragma unroll
    for (int n = 0; n < 16; ++n) h[n] = 0.f;

    for (int j = 0; j < CLEN; ++j) {
        const int m = b * SEQ + l0 + j;
        const float xv = (float)xch[(size_t)m * 1024 + d] + (float)xcl[(size_t)m * 1024 + d];
        const float* pp = &buf[j * 33];
        const float delta = pp[32];
        const float dx = delta * xv;
#pragma unroll
        for (int n = 0; n < 16; ++n)
            h[n] = __expf(delta * a[n]) * h[n] + dx * pp[n];
    }

    __bf16* hp = hbuf + ((size_t)(b * NCHUNK + c) * 1024 + d) * 16;
#pragma unroll
    for (int n = 0; n < 16; ++n) hp[n] = (__bf16)h[n];
}

__global__ __launch_bounds__(256) void scan_phase2(
    const float* __restrict__ A_log,
    const float* __restrict__ S,
    __bf16* __restrict__ hbuf)
{
    const int n = threadIdx.x & 15;
    const int d = blockIdx.x * 16 + (threadIdx.x >> 4);
    const int b = blockIdx.y;
    const float a = -__expf(A_log[d * 16 + n]);
    float h = 0.f;
    for (int c = 0; c < NCHUNK; ++c) {
        const size_t off = ((size_t)(b * NCHUNK + c) * 1024 + d) * 16 + n;
        const float he = (float)hbuf[off];
        hbuf[off] = (__bf16)h;
        h = __expf(a * S[b * NCHUNK + c]) * h + he;
    }
}

__global__ __launch_bounds__(256) void scan_phase3(
    const float* __restrict__ P,
    const __bf16* __restrict__ xch, const __bf16* __restrict__ xcl,
    const float* __restrict__ xz,
    const float* __restrict__ A_log,
    const float* __restrict__ Dp,
    const __bf16* __restrict__ hbuf,
    __bf16* __restrict__ Y)
{
    const int d = blockIdx.x * 256 + threadIdx.x;
    const int c = blockIdx.y;
    const int b = blockIdx.z;
    const int l0 = c * CLEN;

    __shared__ float buf[CLEN * 33];
    const float* src = P + (size_t)(b * SEQ + l0) * 33;
    for (int idx = threadIdx.x; idx < CLEN * 33; idx += 256)
        buf[idx] = src[idx];
    __syncthreads();

    float a[16];
#pragma unroll
    for (int n = 0; n < 16; ++n) a[n] = -__expf(A_log[d * 16 + n]);
    const float Dv = Dp[d];

    const __bf16* hp = hbuf + ((size_t)(b * NCHUNK + c) * 1024 + d) * 16;
    float h[16];
#pragma unroll
    for (int n = 0; n < 16; ++n) h[n] = (float)hp[n];

    for (int j = 0; j < CLEN; ++j) {
        const int m = b * SEQ + l0 + j;
        const float xv = (float)xch[(size_t)m * 1024 + d] + (float)xcl[(size_t)m * 1024 + d];
        const float zv = xz[(size_t)m * 2048 + 1024 + d];
        const float* pp = &buf[j * 33];
        const float delta = pp[32];
        const float dx = delta * xv;
        float y = 0.f;
#pragma unroll
        for (int n = 0; n < 16; ++n) {
            h[n] = __expf(delta * a[n]) * h[n] + dx * pp[n];
            y += h[n] * pp[16 + n];
        }
        y += Dv * xv;
        const float sz = zv / (1.f + __expf(-zv));
        Y[(size_t)m * 1024 + d] = (__bf16)(y * sz);
    }
}

// ---------------------------------------------------------------
extern "C" void kernel_launch(void* const* d_in, const int* in_sizes, int n_in,
                              void* d_out, int out_size, void* d_ws, size_t ws_size,
                              hipStream_t stream) {
    const float* x          = (const float*)d_in[0];
    const float* in_proj_w  = (const float*)d_in[1];
    const float* conv_w     = (const float*)d_in[2];
    const float* conv_b     = (const float*)d_in[3];
    const float* x_proj_w   = (const float*)d_in[4];
    const float* A_log      = (const float*)d_in[5];
    const float* D_param    = (const float*)d_in[6];
    const float* out_proj_w = (const float*)d_in[7];
    float* out = (float*)d_out;

    char* ws = (char*)d_ws;
    // Lifetimes:
    //  t0 cvt_all     -> x_hi, wi_hi/lo, wo, wxh/wxl, cwT
    //  t1 in_proj     reads x_hi, wi_* -> xz
    //  t2a conv_silu  reads xz, cwT    -> xch (over x_hi), xcl
    //  t2b xproj_gemm reads xch/xcl, wxh/wxl -> P (over wi_hi)
    //  t3 scans       reads P, xch/xcl, xz -> hbuf, y (over wxh/wxl/cwT)
    //  t4 out_proj    reads y, wo -> out
    // NOTE (R6 bug fix): cwT must NOT live inside wi_lo's region —
    // both are written by the same cvt_all dispatch. It now sits in
    // the y-region head, after wxl (dead only at t3 when y lands).
    float*  xz     = (float*)(ws);                 // [0, 64M)
    __bf16* x_hi   = (__bf16*)(ws + 67108864);     // [64M, 80M)
    __bf16* xch    = (__bf16*)(ws + 67108864);     // t2a+: over x_hi
    __bf16* xcl    = (__bf16*)(ws + 83886080);     // [80M, 96M)
    __bf16* wi_hi  = (__bf16*)(ws + 100663296);    // [96M, 100M)
    __bf16* wi_lo  = (__bf16*)(ws + 104857600);    // [100M, 104M)
    float*  params = (float*)(ws + 100663296);     // t2b+: over wi_hi (1.08 MB)
    __bf16* hbuf   = (__bf16*)(ws + 101744640);    // t3: 4 MiB (over dead wi_* tail)
    float*  Sbuf   = (float*)(ws + 105938944);     // t3: 512 B (over dead wi_lo)
    __bf16* y      = (__bf16*)(ws + 109051904);    // t3+: 16 MiB
    __bf16* wxh    = (__bf16*)(ws + 109051904);    // t0-t2b: head of y region
    __bf16* wxl    = (__bf16*)(ws + 109150208);    //   96 KB each
    float*  cwT    = (float*)(ws + 109248512);     // t0-t2a: 16 KB, after wxl
    __bf16* wo     = (__bf16*)(ws + 125829120);    // 2 MiB

    // 0) conversions
    cvt_all<<<(NTOT + 255) / 256, 256, 0, stream>>>(
        x, in_proj_w, out_proj_w, x_proj_w, conv_w,
        x_hi, wi_hi, wi_lo, wo, wxh, wxl, cwT);

    // 1) in_proj (M=8192,N=2048,K=1024)
    gemm256_bsplit<<<dim3(2048 / 256, M_ROWS / 256), 512, 0, stream>>>(
        x_hi, wi_hi, wi_lo, xz);

    // 2a) conv+bias+SiLU -> xch/xcl
    conv_silu<<<M_ROWS, 256, 0, stream>>>(xz, cwT, conv_b, xch, xcl);

    // 2b) x_proj (+softplus) via MFMA
    xproj_gemm<<<M_ROWS / 32, 128, 0, stream>>>(xch, xcl, wxh, wxl, params);

    // 3) chunked parallel scan
    scan_phase1<<<dim3(DMODEL / 256, NCHUNK, BATCH), 256, 0, stream>>>(
        params, xch, xcl, A_log, hbuf, Sbuf);
    scan_phase2<<<dim3(DMODEL / 16, BATCH), 256, 0, stream>>>(
        A_log, Sbuf, hbuf);
    scan_phase3<<<dim3(DMODEL / 256, NCHUNK, BATCH), 256, 0, stream>>>(
        params, xch, xcl, xz, A_log, D_param, hbuf, y);

    // 4) out_proj (M=8192,N=1024,K=1024)
    gemm_pipe<false, 128><<<dim3(1024 / 128, M_ROWS / 128), 512, 0, stream>>>(
        y, wo, nullptr, out, DMODEL, 1024);
}